// Round 1
// 208.043 us; speedup vs baseline: 1.0172x; 1.0172x over previous
//
#include <hip/hip_runtime.h>
#include <math.h>

// ---------------- types / helpers ----------------
typedef float f32x4 __attribute__((ext_vector_type(4)));
typedef __bf16 bf16x8 __attribute__((ext_vector_type(8)));
typedef unsigned short ushort_t;

#define MFMA16(a, b, c) __builtin_amdgcn_mfma_f32_16x16x32_bf16((a), (b), (c), 0, 0, 0)

static __device__ __forceinline__ ushort_t f2bf(float f) {
  union { float f; unsigned u; } v; v.f = f;
  unsigned u = v.u;
  return (ushort_t)((u + 0x7FFFu + ((u >> 16) & 1u)) >> 16);  // RNE
}
static __device__ __forceinline__ float bf2f(ushort_t h) {
  union { unsigned u; float f; } v; v.u = ((unsigned)h) << 16;
  return v.f;
}
// async global->LDS, 16B per lane; lds pointer must be wave-uniform (dest = base + lane*16)
static __device__ __forceinline__ void gl_lds16(const void* g, void* lds_uniform) {
  __builtin_amdgcn_global_load_lds(
      (const __attribute__((address_space(1))) unsigned int*)g,
      (__attribute__((address_space(3))) unsigned int*)lds_uniform, 16, 0, 0);
}

// ---------------- fused prep: x/w casts + RoPE table (1 launch) ----------
__global__ void prep(const float* __restrict__ x,
                     const float* __restrict__ wq, const float* __restrict__ wk,
                     const float* __restrict__ wv, const float* __restrict__ wo,
                     ushort_t* __restrict__ Xb, ushort_t* __restrict__ Wqb,
                     ushort_t* __restrict__ Wkb, ushort_t* __restrict__ Wvb,
                     ushort_t* __restrict__ Wob, float2* __restrict__ cs) {
  const int bid = blockIdx.x;
  if (bid < 12288) {
    const float* src;
    ushort_t* dst;
    int i;
    if (bid < 8192) {
      src = x; dst = Xb;
      i = bid * 256 + threadIdx.x;
    } else {
      const int wi = (bid - 8192) >> 10;
      src = (wi == 0) ? wq : (wi == 1) ? wk : (wi == 2) ? wv : wo;
      dst = (wi == 0) ? Wqb : (wi == 1) ? Wkb : (wi == 2) ? Wvb : Wob;
      i = ((bid - 8192) & 1023) * 256 + threadIdx.x;
    }
    f32x4 v = ((const f32x4*)src)[i];
    ushort4 o;
    o.x = f2bf(v.x); o.y = f2bf(v.y); o.z = f2bf(v.z); o.w = f2bf(v.w);
    ((ushort4*)dst)[i] = o;
  } else {
    int idx = (bid - 12288) * 256 + threadIdx.x;  // 4096*32 entries
    int pos = idx >> 5, i = idx & 31;
    double inv = exp2(-(double)i * 0.41524101186092029);  // log2(10000)/32
    double th = (double)pos * inv;
    double s, c;
    sincos(th, &s, &c);
    cs[idx] = make_float2((float)c, (float)s);
  }
}

// ---------------- pipelined NT GEMM (T3+T4+T5) ----------------
// BM=256, BN=128, BK=64. 512 threads = 8 waves (4M x 2N), per-wave 64x64 output.
// C[m][n] = sum_k A[m][k]*W[n][k]. A: MxK bf16 rm, W: NxK bf16 rm.
// LDS 96 KiB: A dbuf 2x32K @0, B dbuf 2x16K @65536. XOR-swizzled chunk layout
// (slot = chunk ^ (row&7)) via pre-swizzled global source (same scheme as the
// verified 0-conflict 128^2 kernel).
//
// Schedule per K-tile j (2 phases of 16 MFMA, counted vmcnt, never 0 mid-loop):
//  P0: ds_read A m0-3 ks01 (8) + B n0-1 ks01 (4); issue B(j+1)->other buf [2]
//      bar; lgkm0; prio1; 16 MFMA; prio0; bar
//  P1: ds_read B n2-3 ks01 (4); issue A(j+2)->cur buf [4] (A region freed by P0);
//      vmcnt(4)  [outstanding 10 -> retire tile j+1's 6, keep 4 in flight]
//      bar; lgkm0; prio1; 16 MFMA; prio0; bar
// Invariants: A(cur) consumed after P0 (held in regs through P1); B(cur) after P1;
// B(other) last read at j-1 P1 -> writable at j P0. vmcnt in-order retirement
// guarantees tile j+1 fully landed before its P0 reads.
template <int OUTBF>
__global__ __launch_bounds__(512, 2) void gemm8(
    const ushort_t* __restrict__ A,
    const ushort_t* __restrict__ W0, const ushort_t* __restrict__ W1, const ushort_t* __restrict__ W2,
    void* __restrict__ C0, void* __restrict__ C1, void* __restrict__ C2,
    int K, int N) {
  __shared__ __align__(16) char smem[98304];
  const int z = blockIdx.z;
  const ushort_t* W = (z == 0) ? W0 : (z == 1 ? W1 : W2);
  void* Cv = (z == 0) ? C0 : (z == 1 ? C1 : C2);

  const int t = threadIdx.x;
  const int lane = t & 63;
  const int l15 = lane & 15, quad = lane >> 4;
  const int wave = t >> 6;
  const int wm = wave >> 1, wn = wave & 1;
  const int bm = blockIdx.x, bn = blockIdx.y;

  // staging: thread t -> row t>>3 (of 64 per load), LDS chunk t&7, global chunk (t&7)^(row&7)
  const int r0 = t >> 3;
  const int gc = (t & 7) ^ (r0 & 7);
  const ushort_t* Ag = A + (size_t)(bm * 256 + r0) * K + gc * 8;
  const ushort_t* Wg = W + (size_t)(bn * 128 + r0) * K + gc * 8;
  const size_t p64K = (size_t)64 * K;
  char* ldsw = smem + wave * 1024;  // wave-uniform dest base (+ lane*16 by HW)

  // fragment read offsets (bytes). slot = (ks*4+quad) ^ (l15&7); ks1 = ks0 ^ bit6.
  const int sl0 = (quad ^ (l15 & 7)) * 16;
  const int aoff = (wm * 64 + l15) * 128 + sl0;           // + m*2048, ^64 for ks1, + buf*32768
  const int boff = 65536 + (wn * 64 + l15) * 128 + sl0;   // + n*2048, ^64 for ks1, + buf*16384

  const int KT = K >> 6;  // requires KT >= 3

  const f32x4 zero4 = {0.f, 0.f, 0.f, 0.f};
  f32x4 acc[4][4];
#pragma unroll
  for (int i = 0; i < 4; ++i)
#pragma unroll
    for (int j = 0; j < 4; ++j) acc[i][j] = zero4;

  auto stA = [&](int buf, int p, int k0) {
    gl_lds16(Ag + p64K * p + k0, ldsw + buf * 32768 + p * 8192);
  };
  auto stB = [&](int buf, int p, int k0) {
    gl_lds16(Wg + p64K * p + k0, ldsw + 65536 + buf * 16384 + p * 8192);
  };

  // prologue: tile0 full (A4+B2) -> buf0; tile1 A4 -> buf1. 10 issued, wait to 4.
  stA(0, 0, 0); stA(0, 1, 0); stA(0, 2, 0); stA(0, 3, 0);
  stB(0, 0, 0); stB(0, 1, 0);
  stA(1, 0, 64); stA(1, 1, 64); stA(1, 2, 64); stA(1, 3, 64);
  asm volatile("s_waitcnt vmcnt(4)" ::: "memory");
  __builtin_amdgcn_s_barrier();

  bf16x8 af[4][2], bfr[4][2];

  for (int j = 0; j < KT; ++j) {
    const int cb = j & 1, nb = cb ^ 1;
    const char* Ab = smem + cb * 32768;
    const char* Bb = smem + cb * 16384;  // boff already carries +65536

    // ---- P0 ----
#pragma unroll
    for (int m = 0; m < 4; ++m) {
      const int o = aoff + m * 2048;
      af[m][0] = *(const bf16x8*)(Ab + o);
      af[m][1] = *(const bf16x8*)(Ab + (o ^ 64));
    }
#pragma unroll
    for (int n = 0; n < 2; ++n) {
      const int o = boff + n * 2048;
      bfr[n][0] = *(const bf16x8*)(Bb + o);
      bfr[n][1] = *(const bf16x8*)(Bb + (o ^ 64));
    }
    if (j + 1 < KT) {
      stB(nb, 0, (j + 1) * 64);
      stB(nb, 1, (j + 1) * 64);
    }
    __builtin_amdgcn_s_barrier();
    asm volatile("s_waitcnt lgkmcnt(0)" ::: "memory");
    __builtin_amdgcn_sched_barrier(0);
    __builtin_amdgcn_s_setprio(1);
#pragma unroll
    for (int m = 0; m < 4; ++m)
#pragma unroll
      for (int n = 0; n < 2; ++n) {
        acc[m][n] = MFMA16(af[m][0], bfr[n][0], acc[m][n]);
        acc[m][n] = MFMA16(af[m][1], bfr[n][1], acc[m][n]);
      }
    __builtin_amdgcn_s_setprio(0);
    __builtin_amdgcn_sched_barrier(0);
    __builtin_amdgcn_s_barrier();

    // ---- P1 ----
#pragma unroll
    for (int n = 2; n < 4; ++n) {
      const int o = boff + n * 2048;
      bfr[n][0] = *(const bf16x8*)(Bb + o);
      bfr[n][1] = *(const bf16x8*)(Bb + (o ^ 64));
    }
    if (j + 2 < KT) {
      stA(cb, 0, (j + 2) * 64);
      stA(cb, 1, (j + 2) * 64);
      stA(cb, 2, (j + 2) * 64);
      stA(cb, 3, (j + 2) * 64);
      asm volatile("s_waitcnt vmcnt(4)" ::: "memory");
    } else if (j + 1 < KT) {
      asm volatile("s_waitcnt vmcnt(0)" ::: "memory");
    }
    __builtin_amdgcn_s_barrier();
    asm volatile("s_waitcnt lgkmcnt(0)" ::: "memory");
    __builtin_amdgcn_sched_barrier(0);
    __builtin_amdgcn_s_setprio(1);
#pragma unroll
    for (int m = 0; m < 4; ++m)
#pragma unroll
      for (int n = 2; n < 4; ++n) {
        acc[m][n] = MFMA16(af[m][0], bfr[n][0], acc[m][n]);
        acc[m][n] = MFMA16(af[m][1], bfr[n][1], acc[m][n]);
      }
    __builtin_amdgcn_s_setprio(0);
    __builtin_amdgcn_sched_barrier(0);
    __builtin_amdgcn_s_barrier();
  }

  // ---- epilogue: C/D mapping col=l15, row=quad*4+r (verified) ----
  const int rbase = bm * 256 + wm * 64 + quad * 4;
  const int cbase = bn * 128 + wn * 64 + l15;
#pragma unroll
  for (int m = 0; m < 4; ++m)
#pragma unroll
    for (int n = 0; n < 4; ++n)
#pragma unroll
      for (int r = 0; r < 4; ++r) {
        size_t idx = (size_t)(rbase + m * 16 + r) * N + (cbase + n * 16);
        if (OUTBF)
          ((ushort_t*)Cv)[idx] = f2bf(acc[m][n][r]);
        else
          ((float*)Cv)[idx] = acc[m][n][r];
      }
}

// ---------------- fused windowed attention (unchanged) ----------------
static __device__ __forceinline__ void rope8(const ushort_t* __restrict__ g,
                                             ushort_t* __restrict__ lds,
                                             const float2* __restrict__ cs4, float scale) {
  uint4 raw = *(const uint4*)g;
  unsigned rw[4] = {raw.x, raw.y, raw.z, raw.w};
  ushort_t o[8];
#pragma unroll
  for (int m = 0; m < 4; ++m) {
    float x1 = bf2f((ushort_t)(rw[m] & 0xffffu));
    float x2 = bf2f((ushort_t)(rw[m] >> 16));
    float2 sc = cs4[m];
    o[2 * m]     = f2bf((x1 * sc.x - x2 * sc.y) * scale);
    o[2 * m + 1] = f2bf((x1 * sc.y + x2 * sc.x) * scale);
  }
  uint4 w;
  w.x = (unsigned)o[0] | ((unsigned)o[1] << 16);
  w.y = (unsigned)o[2] | ((unsigned)o[3] << 16);
  w.z = (unsigned)o[4] | ((unsigned)o[5] << 16);
  w.w = (unsigned)o[6] | ((unsigned)o[7] << 16);
  *(uint4*)lds = w;  // ds_write_b128
}

__global__ __launch_bounds__(256, 2) void attn(
    const ushort_t* __restrict__ Qb, const ushort_t* __restrict__ Kb,
    const ushort_t* __restrict__ Vb, ushort_t* __restrict__ Yb,
    const float2* __restrict__ cs) {
  __shared__ __align__(16) ushort_t smem[27648];
  ushort_t* Qs = smem;
  ushort_t* Ks = smem + 9216;
  ushort_t* Vt = smem;
  ushort_t* Pc = smem + 16896;

  const int t = threadIdx.x;
  const int lane = t & 63, wave = t >> 6;
  const int l15 = lane & 15, quad = lane >> 4;
  const int win = blockIdx.x >> 1, slice = blockIdx.x & 1;
  const int h = blockIdx.y, b = blockIdx.z;
  const int kBase = win * 256, qBase = kBase + slice * 128;
  const size_t gbase = ((size_t)b * 4096) * 1024 + h * 64;

  const int sr = t >> 3;
  const int c0 = (t & 7) * 8;

#pragma unroll
  for (int p = 0; p < 4; ++p) {
    int r = p * 32 + sr;
    rope8(Qb + gbase + (size_t)(qBase + r) * 1024 + c0, Qs + r * 72 + c0,
          cs + (qBase + r) * 32 + (c0 >> 1), 0.125f);
  }
#pragma unroll
  for (int p = 0; p < 8; ++p) {
    int r = p * 32 + sr;
    rope8(Kb + gbase + (size_t)(kBase + r) * 1024 + c0, Ks + r * 72 + c0,
          cs + (kBase + r) * 32 + (c0 >> 1), 1.0f);
  }
  __syncthreads();

  const int qw = wave * 32;
  const f32x4 zero4 = {0.f, 0.f, 0.f, 0.f};
  f32x4 S[2][16];
#pragma unroll
  for (int i = 0; i < 2; ++i)
#pragma unroll
    for (int j = 0; j < 16; ++j) S[i][j] = zero4;
#pragma unroll
  for (int ks = 0; ks < 2; ++ks) {
    bf16x8 a0 = *(const bf16x8*)&Qs[(qw + l15) * 72 + ks * 32 + quad * 8];
    bf16x8 a1 = *(const bf16x8*)&Qs[(qw + 16 + l15) * 72 + ks * 32 + quad * 8];
#pragma unroll
    for (int j = 0; j < 16; ++j) {
      bf16x8 bk = *(const bf16x8*)&Ks[(j * 16 + l15) * 72 + ks * 32 + quad * 8];
      S[0][j] = MFMA16(a0, bk, S[0][j]);
      S[1][j] = MFMA16(a1, bk, S[1][j]);
    }
  }

  float linv[2][4];
#pragma unroll
  for (int i = 0; i < 2; ++i)
#pragma unroll
    for (int r = 0; r < 4; ++r) {
      float mx = S[i][0][r];
#pragma unroll
      for (int j = 1; j < 16; ++j) mx = fmaxf(mx, S[i][j][r]);
      mx = fmaxf(mx, __shfl_xor(mx, 1));
      mx = fmaxf(mx, __shfl_xor(mx, 2));
      mx = fmaxf(mx, __shfl_xor(mx, 4));
      mx = fmaxf(mx, __shfl_xor(mx, 8));
      float sum = 0.f;
#pragma unroll
      for (int j = 0; j < 16; ++j) {
        float e = __expf(S[i][j][r] - mx);
        S[i][j][r] = e;
        sum += e;
      }
      sum += __shfl_xor(sum, 1);
      sum += __shfl_xor(sum, 2);
      sum += __shfl_xor(sum, 4);
      sum += __shfl_xor(sum, 8);
      linv[i][r] = 1.0f / sum;
    }
  __syncthreads();

#pragma unroll
  for (int p = 0; p < 8; ++p) {
    int k = p * 32 + sr;
    uint4 raw = *(const uint4*)(Vb + gbase + (size_t)(kBase + k) * 1024 + c0);
    ushort_t vv[8];
    vv[0] = raw.x & 0xffffu; vv[1] = raw.x >> 16;
    vv[2] = raw.y & 0xffffu; vv[3] = raw.y >> 16;
    vv[4] = raw.z & 0xffffu; vv[5] = raw.z >> 16;
    vv[6] = raw.w & 0xffffu; vv[7] = raw.w >> 16;
#pragma unroll
    for (int e = 0; e < 8; ++e) {
      int ee = (e + (t & 7)) & 7;
      Vt[(c0 + ee) * 264 + k] = vv[ee];
    }
  }

  auto writeP = [&](int kc) {
#pragma unroll
    for (int i = 0; i < 2; ++i)
#pragma unroll
      for (int jj = 0; jj < 4; ++jj) {
        int j = kc * 4 + jj;
#pragma unroll
        for (int r = 0; r < 4; ++r)
          Pc[(qw + i * 16 + quad * 4 + r) * 72 + jj * 16 + l15] = f2bf(S[i][j][r]);
      }
  };

  writeP(0);
  __syncthreads();

  f32x4 O[2][4];
#pragma unroll
  for (int i = 0; i < 2; ++i)
#pragma unroll
    for (int jd = 0; jd < 4; ++jd) O[i][jd] = zero4;

  for (int kc = 0; kc < 4; ++kc) {
#pragma unroll
    for (int ks = 0; ks < 2; ++ks) {
      bf16x8 a0 = *(const bf16x8*)&Pc[(qw + l15) * 72 + ks * 32 + quad * 8];
      bf16x8 a1 = *(const bf16x8*)&Pc[(qw + 16 + l15) * 72 + ks * 32 + quad * 8];
#pragma unroll
      for (int jd = 0; jd < 4; ++jd) {
        bf16x8 bv = *(const bf16x8*)&Vt[(jd * 16 + l15) * 264 + kc * 64 + ks * 32 + quad * 8];
        O[0][jd] = MFMA16(a0, bv, O[0][jd]);
        O[1][jd] = MFMA16(a1, bv, O[1][jd]);
      }
    }
    if (kc < 3) {
      __syncthreads();
      writeP(kc + 1);
      __syncthreads();
    }
  }

#pragma unroll
  for (int i = 0; i < 2; ++i)
#pragma unroll
    for (int jd = 0; jd < 4; ++jd)
#pragma unroll
      for (int r = 0; r < 4; ++r) {
        int row = qBase + qw + i * 16 + quad * 4 + r;
        int col = jd * 16 + l15;
        Yb[gbase + (size_t)row * 1024 + col] = f2bf(O[i][jd][r] * linv[i][r]);
      }
}

// ---------------- launch ----------------
extern "C" void kernel_launch(void* const* d_in, const int* in_sizes, int n_in,
                              void* d_out, int out_size, void* d_ws, size_t ws_size,
                              hipStream_t stream) {
  (void)in_sizes; (void)n_in; (void)out_size; (void)ws_size;
  const float* x  = (const float*)d_in[0];
  const float* wq = (const float*)d_in[1];
  const float* wk = (const float*)d_in[2];
  const float* wv = (const float*)d_in[3];
  const float* wo = (const float*)d_in[4];

  char* ws = (char*)d_ws;
  // workspace layout (bytes): Xb 16M | Wq..Wo 4x2M | Qb 16M | Kb 16M | Vb 16M | Yb 16M | cs 1M
  ushort_t* Xb  = (ushort_t*)(ws);
  ushort_t* Wqb = (ushort_t*)(ws + 16777216);
  ushort_t* Wkb = Wqb + 1048576;
  ushort_t* Wvb = Wkb + 1048576;
  ushort_t* Wob = Wvb + 1048576;
  ushort_t* Qb  = (ushort_t*)(ws + 25165824);
  ushort_t* Kb  = Qb + 8388608;
  ushort_t* Vb  = Kb + 8388608;
  ushort_t* Yb  = Vb + 8388608;
  float2*   cs  = (float2*)(ws + 92274688);

  prep<<<dim3(12800), dim3(256), 0, stream>>>(x, wq, wk, wv, wo,
                                              Xb, Wqb, Wkb, Wvb, Wob, cs);

  // QKV: M=8192, N=1024 per weight -> 32x8x3 = 768 blocks = 3 perfect rounds @ 1 blk/CU
  gemm8<1><<<dim3(32, 8, 3), dim3(512), 0, stream>>>(
      Xb, Wqb, Wkb, Wvb, (void*)Qb, (void*)Kb, (void*)Vb, 1024, 1024);

  attn<<<dim3(32, 16, 2), dim3(256), 0, stream>>>(Qb, Kb, Vb, Yb, cs);

  // proj: 32x8x1 = 256 blocks = 1 perfect round
  gemm8<0><<<dim3(32, 8, 1), dim3(512), 0, stream>>>(
      Yb, Wob, Wob, Wob, d_out, d_out, d_out, 1024, 1024);
}